// Round 2
// baseline (9302.402 us; speedup 1.0000x reference)
//
#include <hip/hip_runtime.h>
#include <cstdio>

#define NN 50000
#define NE 640000
#define NG 256
#define HD 128
#define NL 4

typedef unsigned short u16;

static __device__ __forceinline__ float bf2f(u16 v) {
    return __uint_as_float(((unsigned int)v) << 16);
}
static __device__ __forceinline__ u16 f2bf(float f) {
    unsigned int u = __float_as_uint(f);
    u += 0x7fff + ((u >> 16) & 1);   // round-to-nearest-even
    return (u16)(u >> 16);
}

// ---------------- kernel 1: node embed  h = cat(x,p) @ W_embed + b ----------------
__global__ __launch_bounds__(256) void k_node_embed(
    const float* __restrict__ x, const float* __restrict__ p,
    const float* __restrict__ W, const float* __restrict__ b,
    float* __restrict__ h)
{
    __shared__ float row[2][80];
    const int t = threadIdx.x;
    const int nl = t >> 7;
    const int col = t & 127;
    const int node = blockIdx.x * 2 + nl;
    if (col < 64)       row[nl][col] = x[node * 64 + col];
    else if (col < 80)  row[nl][col] = p[node * 16 + (col - 64)];
    __syncthreads();
    float acc = b[col];
    #pragma unroll 8
    for (int k = 0; k < 80; ++k) acc += row[nl][k] * W[k * 128 + col];
    h[(size_t)node * 128 + col] = acc;
}

// ---------------- kernel 2: edge embed  e = e_attr @ W_ee + b  (bf16 out) ----------------
__global__ __launch_bounds__(256) void k_edge_embed(
    const float* __restrict__ ea, const float* __restrict__ W,
    const float* __restrict__ b, u16* __restrict__ e)
{
    __shared__ float row[2][16];
    const int t = threadIdx.x;
    const int el = t >> 7;
    const int col = t & 127;
    const int edge = blockIdx.x * 2 + el;
    if (col < 16) row[el][col] = ea[edge * 16 + col];
    __syncthreads();
    float acc = b[col];
    #pragma unroll
    for (int k = 0; k < 16; ++k) acc += row[el][k] * W[k * 128 + col];
    e[(size_t)edge * 128 + col] = f2bf(acc);
}

// ---------------- kernel 3: fused edge messages + e update ----------------
// 16 edges/block. At[k][j] transposed in LDS, row stride 20 (16B-aligned, banks spread).
// One [16,384]@[384,256] GEMM: cols 0..127 -> messages (atomicAdd into agg, +bm per
// edge BEFORE aggregation), cols 128..255 -> e_new (+be), stored bf16 in place.
__global__ __launch_bounds__(256) void k_edge(
    const float* __restrict__ h, u16* __restrict__ e,
    float* __restrict__ agg,
    const int* __restrict__ send, const int* __restrict__ rec,
    const float* __restrict__ Wm, const float* __restrict__ bm,
    const float* __restrict__ We, const float* __restrict__ be)
{
    __shared__ float At[384 * 20];
    const int t = threadIdx.x;
    const int E0 = blockIdx.x * 16;

    {
        const int j2 = t >> 7;
        const int col = t & 127;
        #pragma unroll
        for (int i = 0; i < 8; ++i) {
            const int j = j2 + 2 * i;
            const int eidx = E0 + j;
            const int s = send[eidx], r = rec[eidx];
            At[col * 20 + j]         = h[(size_t)s * 128 + col];
            At[(128 + col) * 20 + j] = h[(size_t)r * 128 + col];
            At[(256 + col) * 20 + j] = bf2f(e[(size_t)eidx * 128 + col]);
        }
    }
    __syncthreads();

    const int eg = t >> 6;          // 0..3, owns 4 edges
    const int cg = t & 63;          // 0..63, owns 4 of 256 cols
    const float* Wsel = (cg < 32) ? (Wm + cg * 4) : (We + (cg - 32) * 4);

    float acc[4][4];
    #pragma unroll
    for (int i = 0; i < 4; ++i)
        #pragma unroll
        for (int c = 0; c < 4; ++c) acc[i][c] = 0.f;

    #pragma unroll 4
    for (int k = 0; k < 384; ++k) {
        const float4 av = *reinterpret_cast<const float4*>(&At[k * 20 + eg * 4]);
        const float4 wv = *reinterpret_cast<const float4*>(&Wsel[(size_t)k * 128]);
        const float a[4] = {av.x, av.y, av.z, av.w};
        const float w[4] = {wv.x, wv.y, wv.z, wv.w};
        #pragma unroll
        for (int i = 0; i < 4; ++i)
            #pragma unroll
            for (int c = 0; c < 4; ++c)
                acc[i][c] += a[i] * w[c];
    }

    const int colbase = cg * 4;
    #pragma unroll
    for (int i = 0; i < 4; ++i) {
        const int eidx = E0 + eg * 4 + i;
        if (colbase < 128) {
            const int r = rec[eidx];
            float* dst = agg + (size_t)r * 128 + colbase;
            #pragma unroll
            for (int c = 0; c < 4; ++c)
                atomicAdd(dst + c, acc[i][c] + bm[colbase + c]);
        } else {
            u16* dst = e + (size_t)eidx * 128 + (colbase - 128);
            #pragma unroll
            for (int c = 0; c < 4; ++c)
                dst[c] = f2bf(acc[i][c] + be[colbase - 128 + c]);
        }
    }
}

// ---------------- kernel 4: node update  h = cat(h, agg) @ Wh + bh ----------------
__global__ __launch_bounds__(256) void k_node(
    float* __restrict__ h, const float* __restrict__ agg,
    const float* __restrict__ Wh, const float* __restrict__ bh)
{
    __shared__ float rows[8][256];
    const int t = threadIdx.x;
    const int col = t & 127;
    const int ng = t >> 7;
    const int base = blockIdx.x * 8;
    #pragma unroll
    for (int i = 0; i < 4; ++i) {
        const int nl = ng + 2 * i;
        const int node = base + nl;
        rows[nl][col]       = h[(size_t)node * 128 + col];
        rows[nl][128 + col] = agg[(size_t)node * 128 + col];
    }
    __syncthreads();
    float acc[4] = {bh[col], bh[col], bh[col], bh[col]};
    #pragma unroll 4
    for (int k = 0; k < 256; ++k) {
        const float w = Wh[k * 128 + col];
        #pragma unroll
        for (int i = 0; i < 4; ++i) acc[i] += rows[ng + 2 * i][k] * w;
    }
    #pragma unroll
    for (int i = 0; i < 4; ++i)
        h[(size_t)(base + ng + 2 * i) * 128 + col] = acc[i];
}

// ---------------- kernel 5: pool (segment_sum over batch) ----------------
__global__ __launch_bounds__(256) void k_pool(
    const float* __restrict__ h, const int* __restrict__ batch,
    float* __restrict__ out)
{
    const int t = threadIdx.x;
    const int col = t & 127;
    const int half = t >> 7;
    const int base = blockIdx.x * 64 + half * 32;
    float acc = 0.f;
    int curg = -1;
    for (int i = 0; i < 32; ++i) {
        const int n = base + i;
        if (n >= NN) break;
        const int g = batch[n];
        if (g != curg) {
            if (curg >= 0) atomicAdd(&out[curg * 128 + col], acc);
            curg = g; acc = 0.f;
        }
        acc += h[(size_t)n * 128 + col];
    }
    if (curg >= 0) atomicAdd(&out[curg * 128 + col], acc);
}

extern "C" void kernel_launch(void* const* d_in, const int* in_sizes, int n_in,
                              void* d_out, int out_size, void* d_ws, size_t ws_size,
                              hipStream_t stream)
{
    const float* x       = (const float*)d_in[0];
    const float* p       = (const float*)d_in[1];
    const float* ea      = (const float*)d_in[2];
    const int*   eidx    = (const int*)d_in[3];
    const int*   batch   = (const int*)d_in[4];
    const float* W_embed = (const float*)d_in[5];
    const float* b_embed = (const float*)d_in[6];
    const float* W_ee    = (const float*)d_in[7];
    const float* b_ee    = (const float*)d_in[8];
    const float* Wm      = (const float*)d_in[9];
    const float* bm      = (const float*)d_in[10];
    const float* Wh      = (const float*)d_in[11];
    const float* bh      = (const float*)d_in[12];
    const float* We      = (const float*)d_in[13];
    const float* be      = (const float*)d_in[14];
    const int* send = eidx;
    const int* rec  = eidx + NE;

    // workspace layout: h fp32 | agg fp32 | e bf16
    const size_t h_bytes   = (size_t)NN * 128 * sizeof(float);   // 25.6 MB
    const size_t agg_bytes = (size_t)NN * 128 * sizeof(float);   // 25.6 MB
    const size_t e_bytes   = (size_t)NE * 128 * sizeof(u16);     // 163.84 MB
    const size_t need = h_bytes + agg_bytes + e_bytes;           // 215.04 MB
    if (ws_size < need) {
        // Diagnostic path: deliberately launch nothing -> clean absmax failure
        // (poison preserved) instead of a device fault.
        fprintf(stderr, "[kernel_launch] ws_size=%zu < needed=%zu — skipping\n",
                ws_size, need);
        return;
    }

    char* wsb  = (char*)d_ws;
    float* h   = (float*)wsb;
    float* agg = (float*)(wsb + h_bytes);
    u16*   e   = (u16*)(wsb + h_bytes + agg_bytes);
    float* out = (float*)d_out;

    hipMemsetAsync(d_out, 0, (size_t)NG * HD * sizeof(float), stream);

    k_node_embed<<<NN / 2, 256, 0, stream>>>(x, p, W_embed, b_embed, h);
    k_edge_embed<<<NE / 2, 256, 0, stream>>>(ea, W_ee, b_ee, e);

    for (int l = 0; l < NL; ++l) {
        hipMemsetAsync(agg, 0, agg_bytes, stream);
        k_edge<<<NE / 16, 256, 0, stream>>>(h, e, agg, send, rec,
            Wm + (size_t)l * 384 * 128, bm + (size_t)l * 128,
            We + (size_t)l * 384 * 128, be + (size_t)l * 128);
        k_node<<<NN / 8, 256, 0, stream>>>(h, agg,
            Wh + (size_t)l * 256 * 128, bh + (size_t)l * 128);
    }
    k_pool<<<(NN + 63) / 64, 256, 0, stream>>>(h, batch, out);
}

// Round 3
// 2257.329 us; speedup vs baseline: 4.1210x; 4.1210x over previous
//
#include <hip/hip_runtime.h>
#include <cstdio>

#define NN 50000
#define NE 640000
#define NG 256
#define HD 128
#define NL 4

// ---------------- kernel 1: node embed  h = cat(x,p) @ W_embed + b ----------------
__global__ __launch_bounds__(256) void k_node_embed(
    const float* __restrict__ x, const float* __restrict__ p,
    const float* __restrict__ W, const float* __restrict__ b,
    float* __restrict__ h)
{
    __shared__ float row[2][80];
    const int t = threadIdx.x;
    const int nl = t >> 7;
    const int col = t & 127;
    const int node = blockIdx.x * 2 + nl;
    if (col < 64)       row[nl][col] = x[node * 64 + col];
    else if (col < 80)  row[nl][col] = p[node * 16 + (col - 64)];
    __syncthreads();
    float acc = b[col];
    #pragma unroll 8
    for (int k = 0; k < 80; ++k) acc += row[nl][k] * W[k * 128 + col];
    h[(size_t)node * 128 + col] = acc;
}

// ---------------- kernel 2: deg + Sea = segsum(e_attr, rec) ----------------
__global__ __launch_bounds__(256) void k_deg_sea(
    const float* __restrict__ ea, const int* __restrict__ rec,
    float* __restrict__ Sea, float* __restrict__ deg)
{
    const int t = threadIdx.x;
    const int e = blockIdx.x * 16 + (t >> 4);
    const int c = t & 15;
    const int r = rec[e];
    atomicAdd(&Sea[(size_t)r * 16 + c], ea[(size_t)e * 16 + c]);
    if (c == 0) atomicAdd(&deg[r], 1.0f);
}

// ---------------- kernel 3: Se0 = Sea @ W_ee + deg * b_ee ----------------
__global__ __launch_bounds__(256) void k_se0(
    const float* __restrict__ Sea, const float* __restrict__ deg,
    const float* __restrict__ Wee, const float* __restrict__ bee,
    float* __restrict__ Se)
{
    __shared__ float row[2][16];
    const int t = threadIdx.x;
    const int nl = t >> 7;
    const int col = t & 127;
    const int node = blockIdx.x * 2 + nl;
    if (col < 16) row[nl][col] = Sea[(size_t)node * 16 + col];
    __syncthreads();
    float acc = deg[node] * bee[col];
    #pragma unroll
    for (int k = 0; k < 16; ++k) acc += row[nl][k] * Wee[k * 128 + col];
    Se[(size_t)node * 128 + col] = acc;
}

// ---------------- kernel 4: weight prep ----------------
// W_big[l][512][256]: A-blocks rows = [h | deg*h | Sh | Se]
//   out cols 0:128  (h_{l+1}): [Wh1 ; Wm2@Wh2 ; Wm1@Wh2 ; Wm3@Wh2]
//   out cols 128:256 (Se_{l+1}): [0 ; We2 ; We1 ; We3]
// cvec[l][128] = bm[l] @ Wh2[l]
__global__ __launch_bounds__(256) void k_wprep(
    const float* __restrict__ Wm, const float* __restrict__ Wh,
    const float* __restrict__ We, const float* __restrict__ bm,
    float* __restrict__ Wb, float* __restrict__ cvec)
{
    const int idx = blockIdx.x * 256 + threadIdx.x;
    const int total = 4 * 512 * 256;
    if (idx < total) {
        const int l = idx >> 17;          // 512*256 = 2^17
        const int rem = idx & 131071;
        const int k = rem >> 8;
        const int c = rem & 255;
        const float* Wm_l = Wm + (size_t)l * 384 * 128;
        const float* Wh_l = Wh + (size_t)l * 256 * 128;
        const float* We_l = We + (size_t)l * 384 * 128;
        float v;
        if (k < 128) {
            v = (c < 128) ? Wh_l[k * 128 + c] : 0.f;
        } else {
            const int kk  = (k - 128) & 127;
            const int blk = (k - 128) >> 7;               // 0:dh 1:Sh 2:Se
            const int roff = (blk == 0) ? 128 : (blk == 1) ? 0 : 256;
            if (c < 128) {
                float s = 0.f;
                #pragma unroll 4
                for (int j = 0; j < 128; ++j)
                    s += Wm_l[(roff + kk) * 128 + j] * Wh_l[(128 + j) * 128 + c];
                v = s;
            } else {
                v = We_l[(roff + kk) * 128 + (c - 128)];
            }
        }
        Wb[idx] = v;
    } else if (idx < total + 512) {
        const int r = idx - total;
        const int l = r >> 7;
        const int c = r & 127;
        const float* Wh_l = Wh + (size_t)l * 256 * 128;
        const float* bm_l = bm + l * 128;
        float s = 0.f;
        #pragma unroll 4
        for (int j = 0; j < 128; ++j) s += bm_l[j] * Wh_l[(128 + j) * 128 + c];
        cvec[r] = s;
    }
}

// ---------------- kernel 5: Sh = segsum(h[send], rec)  (the only O(E) work) ----------------
__global__ __launch_bounds__(256) void k_scatter(
    const float* __restrict__ h, const int* __restrict__ send,
    const int* __restrict__ rec, float* __restrict__ Sh)
{
    const int t = threadIdx.x;
    const int e = blockIdx.x * 2 + (t >> 7);
    const int col = t & 127;
    const int s = send[e];
    const int r = rec[e];
    atomicAdd(&Sh[(size_t)r * 128 + col], h[(size_t)s * 128 + col]);
}

// ---------------- kernel 6: dense layer GEMM ----------------
// [h | deg*h | Sh | Se] ([16 rows,512]) @ W_big([512,256]) per block.
// epilogue: cols 0:128 -> h_out (+bh + deg*cvec); cols 128:256 -> Se_out (+deg*be)
__global__ __launch_bounds__(256) void k_dense(
    const float* __restrict__ h, const float* __restrict__ Sh,
    const float* __restrict__ Se, const float* __restrict__ deg,
    const float* __restrict__ Wb, const float* __restrict__ cvec,
    const float* __restrict__ bh, const float* __restrict__ be,
    float* __restrict__ h_out, float* __restrict__ Se_out)
{
    __shared__ float At[512 * 20];   // transposed A-tile, pad-20 rows
    __shared__ float degs[16];
    const int t = threadIdx.x;
    const int n0 = blockIdx.x * 16;

    // stage: thread t -> row j = t&15, k-chunk kq = t>>4 (32 k's, 8 float4)
    {
        const int j = t & 15;
        const int kq = t >> 4;
        const int node = n0 + j;
        const float dg = deg[node];
        if (t < 16) degs[t] = deg[n0 + t];
        #pragma unroll
        for (int q = 0; q < 8; ++q) {
            const int k = kq * 32 + q * 4;
            const float* src;
            float scale = 1.f;
            int kk;
            if (k < 128)      { src = h  + (size_t)node * 128; kk = k; }
            else if (k < 256) { src = h  + (size_t)node * 128; kk = k - 128; scale = dg; }
            else if (k < 384) { src = Sh + (size_t)node * 128; kk = k - 256; }
            else              { src = Se + (size_t)node * 128; kk = k - 384; }
            const float4 v = *reinterpret_cast<const float4*>(src + kk);
            At[(k + 0) * 20 + j] = v.x * scale;
            At[(k + 1) * 20 + j] = v.y * scale;
            At[(k + 2) * 20 + j] = v.z * scale;
            At[(k + 3) * 20 + j] = v.w * scale;
        }
    }
    __syncthreads();

    const int rg = t >> 6;   // 0..3 -> rows rg*4..+3 (uniform per wave -> LDS broadcast)
    const int cg = t & 63;   // cols cg*4..+3 of 256

    float acc[4][4];
    #pragma unroll
    for (int i = 0; i < 4; ++i)
        #pragma unroll
        for (int c = 0; c < 4; ++c) acc[i][c] = 0.f;

    #pragma unroll 4
    for (int k = 0; k < 512; ++k) {
        const float4 av = *reinterpret_cast<const float4*>(&At[k * 20 + rg * 4]);
        const float4 wv = *reinterpret_cast<const float4*>(&Wb[(size_t)k * 256 + cg * 4]);
        const float a[4] = {av.x, av.y, av.z, av.w};
        const float w[4] = {wv.x, wv.y, wv.z, wv.w};
        #pragma unroll
        for (int i = 0; i < 4; ++i)
            #pragma unroll
            for (int c = 0; c < 4; ++c)
                acc[i][c] += a[i] * w[c];
    }

    const int cbase = cg * 4;
    #pragma unroll
    for (int i = 0; i < 4; ++i) {
        const int row = rg * 4 + i;
        const int node = n0 + row;
        const float dgn = degs[row];
        if (cbase < 128) {
            #pragma unroll
            for (int c = 0; c < 4; ++c)
                h_out[(size_t)node * 128 + cbase + c] =
                    acc[i][c] + bh[cbase + c] + dgn * cvec[cbase + c];
        } else {
            const int cb = cbase - 128;
            #pragma unroll
            for (int c = 0; c < 4; ++c)
                Se_out[(size_t)node * 128 + cb + c] =
                    acc[i][c] + dgn * be[cb + c];
        }
    }
}

// ---------------- kernel 7: pool ----------------
__global__ __launch_bounds__(256) void k_pool(
    const float* __restrict__ h, const int* __restrict__ batch,
    float* __restrict__ out)
{
    const int t = threadIdx.x;
    const int col = t & 127;
    const int half = t >> 7;
    const int base = blockIdx.x * 64 + half * 32;
    float acc = 0.f;
    int curg = -1;
    for (int i = 0; i < 32; ++i) {
        const int n = base + i;
        if (n >= NN) break;
        const int g = batch[n];
        if (g != curg) {
            if (curg >= 0) atomicAdd(&out[curg * 128 + col], acc);
            curg = g; acc = 0.f;
        }
        acc += h[(size_t)n * 128 + col];
    }
    if (curg >= 0) atomicAdd(&out[curg * 128 + col], acc);
}

extern "C" void kernel_launch(void* const* d_in, const int* in_sizes, int n_in,
                              void* d_out, int out_size, void* d_ws, size_t ws_size,
                              hipStream_t stream)
{
    const float* x       = (const float*)d_in[0];
    const float* p       = (const float*)d_in[1];
    const float* ea      = (const float*)d_in[2];
    const int*   eidx    = (const int*)d_in[3];
    const int*   batch   = (const int*)d_in[4];
    const float* W_embed = (const float*)d_in[5];
    const float* b_embed = (const float*)d_in[6];
    const float* W_ee    = (const float*)d_in[7];
    const float* b_ee    = (const float*)d_in[8];
    const float* Wm      = (const float*)d_in[9];
    const float* bm      = (const float*)d_in[10];
    const float* Wh      = (const float*)d_in[11];
    const float* bh      = (const float*)d_in[12];
    const float* We      = (const float*)d_in[13];
    const float* be      = (const float*)d_in[14];
    const int* send = eidx;
    const int* rec  = eidx + NE;

    // float-typed workspace layout
    const size_t NH = (size_t)NN * 128;          // 6.4e6 floats
    float* wsf  = (float*)d_ws;
    float* hA   = wsf;
    float* hB   = hA + NH;
    float* SeA  = hB + NH;
    float* SeB  = SeA + NH;
    float* Sh   = SeB + NH;
    float* Sea  = Sh + NH;                        // NN*16
    float* deg  = Sea + (size_t)NN * 16;          // NN
    float* Wb   = deg + NN;                       // 4*512*256
    float* cvec = Wb + 4 * 512 * 256;             // 4*128
    const size_t need = (size_t)(cvec + 512 - wsf) * sizeof(float);
    if (ws_size < need) {
        fprintf(stderr, "[kernel_launch] ws_size=%zu < needed=%zu — skipping\n",
                ws_size, need);
        return;
    }

    float* out = (float*)d_out;

    hipMemsetAsync(d_out, 0, (size_t)NG * HD * sizeof(float), stream);
    // zero Sea + deg in one shot (adjacent)
    hipMemsetAsync(Sea, 0, ((size_t)NN * 16 + NN) * sizeof(float), stream);

    k_node_embed<<<NN / 2, 256, 0, stream>>>(x, p, W_embed, b_embed, hA);
    k_deg_sea<<<NE / 16, 256, 0, stream>>>(ea, rec, Sea, deg);
    k_se0<<<NN / 2, 256, 0, stream>>>(Sea, deg, W_ee, b_ee, SeA);
    k_wprep<<<(4 * 512 * 256 + 512 + 255) / 256, 256, 0, stream>>>(Wm, Wh, We, bm, Wb, cvec);

    float* h_cur = hA;  float* h_nxt = hB;
    float* Se_cur = SeA; float* Se_nxt = SeB;
    for (int l = 0; l < NL; ++l) {
        hipMemsetAsync(Sh, 0, NH * sizeof(float), stream);
        k_scatter<<<NE / 2, 256, 0, stream>>>(h_cur, send, rec, Sh);
        k_dense<<<NN / 16, 256, 0, stream>>>(h_cur, Sh, Se_cur, deg,
            Wb + (size_t)l * 512 * 256, cvec + l * 128,
            bh + l * 128, be + l * 128, h_nxt, Se_nxt);
        float* tmp;
        tmp = h_cur;  h_cur  = h_nxt;  h_nxt  = tmp;
        tmp = Se_cur; Se_cur = Se_nxt; Se_nxt = tmp;
    }
    k_pool<<<(NN + 63) / 64, 256, 0, stream>>>(h_cur, batch, out);
}

// Round 4
// 727.093 us; speedup vs baseline: 12.7940x; 3.1046x over previous
//
#include <hip/hip_runtime.h>
#include <cstdio>

#define NN 50000
#define NE 640000
#define NG 256
#define NL 4

typedef unsigned short u16;
typedef unsigned int u32;
typedef __attribute__((ext_vector_type(8))) short short8v;   // 8 bf16 = 4 VGPR
typedef __attribute__((ext_vector_type(4))) float f32x4;

static __device__ __forceinline__ float bf2f(u16 v) {
    return __uint_as_float(((u32)v) << 16);
}
static __device__ __forceinline__ u16 f2bf(float f) {
    u32 u = __float_as_uint(f);
    u += 0x7fff + ((u >> 16) & 1);   // RNE
    return (u16)(u >> 16);
}

// ---------------- k_deg_sea: deg(int) histogram + Sea = segsum(e_attr, rec) ----------------
__global__ __launch_bounds__(256) void k_deg_sea(
    const float* __restrict__ ea, const int* __restrict__ rec,
    float* __restrict__ Sea, int* __restrict__ deg)
{
    const int t = threadIdx.x;
    const int e = blockIdx.x * 16 + (t >> 4);
    const int c = t & 15;
    const int r = rec[e];
    atomicAdd(&Sea[(size_t)r * 16 + c], ea[(size_t)e * 16 + c]);
    if (c == 0) atomicAdd(&deg[r], 1);
}

// ---------------- k_node_embed: h0 = cat(x,p) @ W_embed + b  (bf16 out) ----------------
__global__ __launch_bounds__(256) void k_node_embed(
    const float* __restrict__ x, const float* __restrict__ p,
    const float* __restrict__ W, const float* __restrict__ b,
    u16* __restrict__ h)
{
    __shared__ float row[2][80];
    const int t = threadIdx.x;
    const int nl = t >> 7;
    const int col = t & 127;
    const int node = blockIdx.x * 2 + nl;
    if (col < 64)       row[nl][col] = x[node * 64 + col];
    else if (col < 80)  row[nl][col] = p[node * 16 + (col - 64)];
    __syncthreads();
    float acc = b[col];
    #pragma unroll 8
    for (int k = 0; k < 80; ++k) acc += row[nl][k] * W[k * 128 + col];
    h[(size_t)node * 128 + col] = f2bf(acc);
}

// ---------------- k_se0: Se0 = Sea @ W_ee + deg * b_ee  (bf16 out) ----------------
__global__ __launch_bounds__(256) void k_se0(
    const float* __restrict__ Sea, const int* __restrict__ deg,
    const float* __restrict__ Wee, const float* __restrict__ bee,
    u16* __restrict__ Se)
{
    __shared__ float row[2][16];
    const int t = threadIdx.x;
    const int nl = t >> 7;
    const int col = t & 127;
    const int node = blockIdx.x * 2 + nl;
    if (col < 16) row[nl][col] = Sea[(size_t)node * 16 + col];
    __syncthreads();
    float acc = (float)deg[node] * bee[col];
    #pragma unroll
    for (int k = 0; k < 16; ++k) acc += row[nl][k] * Wee[k * 128 + col];
    Se[(size_t)node * 128 + col] = f2bf(acc);
}

// ---------------- k_dh0: dh = deg * h (bf16, ushort2-wise) ----------------
__global__ __launch_bounds__(256) void k_dh0(
    const u16* __restrict__ h, const int* __restrict__ deg, u16* __restrict__ dh)
{
    const int idx = blockIdx.x * 256 + threadIdx.x;   // over NN*64 u32s
    const int row = idx >> 6;
    const float dg = (float)deg[row];
    const u32 v = ((const u32*)h)[idx];
    const float x0 = bf2f((u16)(v & 0xffff)) * dg;
    const float x1 = bf2f((u16)(v >> 16)) * dg;
    ((u32*)dh)[idx] = (u32)f2bf(x0) | ((u32)f2bf(x1) << 16);
}

// ---------------- k_wprep: build Wb fp32 [l][512][256] + cvec ----------------
// A rows = [h | dh | Sh | Se];
// cols 0:128 (h'):  [Wh1 ; Wm2@Wh2 ; Wm1@Wh2 ; Wm3@Wh2]; cols 128:256 (Se'): [0 ; We2 ; We1 ; We3]
__global__ __launch_bounds__(256) void k_wprep(
    const float* __restrict__ Wm, const float* __restrict__ Wh,
    const float* __restrict__ We, const float* __restrict__ bm,
    float* __restrict__ Wb, float* __restrict__ cvec)
{
    const int idx = blockIdx.x * 256 + threadIdx.x;
    const int total = 4 * 512 * 256;
    if (idx < total) {
        const int l = idx >> 17;
        const int rem = idx & 131071;
        const int k = rem >> 8;
        const int c = rem & 255;
        const float* Wm_l = Wm + (size_t)l * 384 * 128;
        const float* Wh_l = Wh + (size_t)l * 256 * 128;
        const float* We_l = We + (size_t)l * 384 * 128;
        float v;
        if (k < 128) {
            v = (c < 128) ? Wh_l[k * 128 + c] : 0.f;
        } else {
            const int kk  = (k - 128) & 127;
            const int blk = (k - 128) >> 7;               // 0:dh 1:Sh 2:Se
            const int roff = (blk == 0) ? 128 : (blk == 1) ? 0 : 256;
            if (c < 128) {
                float s = 0.f;
                #pragma unroll 4
                for (int j = 0; j < 128; ++j)
                    s += Wm_l[(roff + kk) * 128 + j] * Wh_l[(128 + j) * 128 + c];
                v = s;
            } else {
                v = We_l[(roff + kk) * 128 + (c - 128)];
            }
        }
        Wb[idx] = v;
    } else if (idx < total + 512) {
        const int r = idx - total;
        const int l = r >> 7;
        const int c = r & 127;
        const float* Wh_l = Wh + (size_t)l * 256 * 128;
        const float* bm_l = bm + l * 128;
        float s = 0.f;
        #pragma unroll 4
        for (int j = 0; j < 128; ++j) s += bm_l[j] * Wh_l[(128 + j) * 128 + c];
        cvec[r] = s;
    }
}

// ---------------- k_wswz: Wb fp32 -> Bp bf16 swizzled [l][k>>5][n][k&31] ----------------
__global__ __launch_bounds__(256) void k_wswz(
    const float* __restrict__ Wb, u16* __restrict__ Bp)
{
    const int idx = blockIdx.x * 256 + threadIdx.x;    // 4*512*256
    const int l = idx >> 17;
    const int rem = idx & 131071;
    const int k = rem >> 8;
    const int n = rem & 255;
    Bp[(((size_t)l * 16 + (k >> 5)) * 256 + n) * 32 + (k & 31)] = f2bf(Wb[idx]);
}

// ---------------- k_scan: exclusive scan of deg -> offs, cursor (single block) ----------------
__global__ __launch_bounds__(256) void k_scan(
    const int* __restrict__ deg, int* __restrict__ offs, int* __restrict__ cursor)
{
    __shared__ int part[256];
    const int t = threadIdx.x;
    const int C = 196;                      // 196*256 = 50176 >= NN
    const int base = t * C;
    int s = 0;
    for (int i = 0; i < C; ++i) {
        const int idx = base + i;
        if (idx < NN) s += deg[idx];
    }
    part[t] = s;
    __syncthreads();
    for (int off = 1; off < 256; off <<= 1) {
        int v = part[t];
        if (t >= off) v += part[t - off];
        __syncthreads();
        part[t] = v;
        __syncthreads();
    }
    int run = (t == 0) ? 0 : part[t - 1];
    for (int i = 0; i < C; ++i) {
        const int idx = base + i;
        if (idx < NN) {
            offs[idx] = run;
            cursor[idx] = run;
            run += deg[idx];
        }
    }
}

// ---------------- k_fill: csr[pos] = send, pos by atomic cursor per receiver ----------------
__global__ __launch_bounds__(256) void k_fill(
    const int* __restrict__ send, const int* __restrict__ rec,
    int* __restrict__ cursor, int* __restrict__ csr)
{
    const int e = blockIdx.x * 256 + threadIdx.x;
    const int r = rec[e];
    const int pos = atomicAdd(&cursor[r], 1);
    csr[pos] = send[e];
}

// ---------------- k_gather: Sh[n] = sum over incoming edges of h[send] (no atomics) ----------------
__global__ __launch_bounds__(256) void k_gather(
    const u16* __restrict__ h, const int* __restrict__ csr,
    const int* __restrict__ offs, const int* __restrict__ deg,
    u16* __restrict__ Sh)
{
    const int t = threadIdx.x;
    const int lane = t & 63;
    const int node = blockIdx.x * 4 + (t >> 6);     // grid 12500*4 = NN exact
    const int off = offs[node];
    const int d = deg[node];
    const u32* hp = (const u32*)h;
    float a0 = 0.f, a1 = 0.f, b0 = 0.f, b1 = 0.f;
    int j = 0;
    for (; j + 2 <= d; j += 2) {
        const int s0 = csr[off + j];
        const int s1 = csr[off + j + 1];
        const u32 v0 = hp[(size_t)s0 * 64 + lane];
        const u32 v1 = hp[(size_t)s1 * 64 + lane];
        a0 += bf2f((u16)(v0 & 0xffff)); a1 += bf2f((u16)(v0 >> 16));
        b0 += bf2f((u16)(v1 & 0xffff)); b1 += bf2f((u16)(v1 >> 16));
    }
    if (j < d) {
        const u32 v0 = hp[(size_t)csr[off + j] * 64 + lane];
        a0 += bf2f((u16)(v0 & 0xffff)); a1 += bf2f((u16)(v0 >> 16));
    }
    a0 += b0; a1 += b1;
    ((u32*)Sh)[(size_t)node * 64 + lane] = (u32)f2bf(a0) | ((u32)f2bf(a1) << 16);
}

// ---------------- k_dense: [h|dh|Sh|Se] @ Wb via bf16 MFMA ----------------
// block = 4 waves; wave (wm,wn): rows rb..rb+31 (2 m-frags), cols wn*128..+127 (8 n-frags).
// A-frags: direct 16B global loads from bf16 state (L2/L3-resident). B-frags from Bp.
// epilogue: cols 0:128 -> h' (+bh+deg*cvec) and dh'=deg*h'; cols 128:256 -> Se' (+deg*be).
__global__ __launch_bounds__(256) void k_dense(
    const u16* __restrict__ h, const u16* __restrict__ dh,
    const u16* __restrict__ Sh, const u16* __restrict__ Se,
    const int* __restrict__ deg, const u16* __restrict__ Bp,
    const float* __restrict__ cvec, const float* __restrict__ bh,
    const float* __restrict__ be,
    u16* __restrict__ h_out, u16* __restrict__ dh_out, u16* __restrict__ Se_out)
{
    const int t = threadIdx.x;
    const int lane = t & 63;
    const int w = t >> 6;
    const int wm = w & 1;
    const int wn = w >> 1;
    const int rb = blockIdx.x * 64 + wm * 32;
    const int cb = wn * 128;
    const int l15 = lane & 15;
    const int kg  = lane >> 4;

    int r0 = rb + l15;      if (r0 > NN - 1) r0 = NN - 1;
    int r1 = rb + 16 + l15; if (r1 > NN - 1) r1 = NN - 1;
    const size_t a0off = (size_t)r0 * 128 + kg * 8;
    const size_t a1off = (size_t)r1 * 128 + kg * 8;

    f32x4 acc[2][8];
    #pragma unroll
    for (int m = 0; m < 2; ++m)
        #pragma unroll
        for (int n = 0; n < 8; ++n) acc[m][n] = (f32x4){0.f, 0.f, 0.f, 0.f};

    #pragma unroll
    for (int s = 0; s < 4; ++s) {
        const u16* __restrict__ Sp = (s == 0) ? h : (s == 1) ? dh : (s == 2) ? Sh : Se;
        #pragma unroll
        for (int k4 = 0; k4 < 4; ++k4) {
            const int ks = s * 4 + k4;     // 0..15
            const short8v a0 = *(const short8v*)(Sp + a0off + k4 * 32);
            const short8v a1 = *(const short8v*)(Sp + a1off + k4 * 32);
            const u16* bb = Bp + (((size_t)ks * 256) + cb + l15) * 32 + kg * 8;
            #pragma unroll
            for (int nf = 0; nf < 8; ++nf) {
                const short8v b = *(const short8v*)(bb + (size_t)nf * 16 * 32);
                acc[0][nf] = __builtin_amdgcn_mfma_f32_16x16x32_bf16(a0, b, acc[0][nf], 0, 0, 0);
                acc[1][nf] = __builtin_amdgcn_mfma_f32_16x16x32_bf16(a1, b, acc[1][nf], 0, 0, 0);
            }
        }
    }

    #pragma unroll
    for (int m = 0; m < 2; ++m) {
        #pragma unroll
        for (int r = 0; r < 4; ++r) {
            const int row = rb + m * 16 + kg * 4 + r;
            if (row < NN) {
                const float dg = (float)deg[row];
                if (cb == 0) {
                    #pragma unroll
                    for (int nf = 0; nf < 8; ++nf) {
                        const int col = nf * 16 + l15;
                        const float v = acc[m][nf][r] + bh[col] + dg * cvec[col];
                        h_out[(size_t)row * 128 + col]  = f2bf(v);
                        dh_out[(size_t)row * 128 + col] = f2bf(v * dg);
                    }
                } else {
                    #pragma unroll
                    for (int nf = 0; nf < 8; ++nf) {
                        const int col = nf * 16 + l15;
                        const float v = acc[m][nf][r] + dg * be[col];
                        Se_out[(size_t)row * 128 + col] = f2bf(v);
                    }
                }
            }
        }
    }
}

// ---------------- k_pool ----------------
__global__ __launch_bounds__(256) void k_pool(
    const u16* __restrict__ h, const int* __restrict__ batch,
    float* __restrict__ out)
{
    const int t = threadIdx.x;
    const int col = t & 127;
    const int half = t >> 7;
    const int base = blockIdx.x * 64 + half * 32;
    float acc = 0.f;
    int curg = -1;
    for (int i = 0; i < 32; ++i) {
        const int n = base + i;
        if (n >= NN) break;
        const int g = batch[n];
        if (g != curg) {
            if (curg >= 0) atomicAdd(&out[curg * 128 + col], acc);
            curg = g; acc = 0.f;
        }
        acc += bf2f(h[(size_t)n * 128 + col]);
    }
    if (curg >= 0) atomicAdd(&out[curg * 128 + col], acc);
}

extern "C" void kernel_launch(void* const* d_in, const int* in_sizes, int n_in,
                              void* d_out, int out_size, void* d_ws, size_t ws_size,
                              hipStream_t stream)
{
    const float* x       = (const float*)d_in[0];
    const float* p       = (const float*)d_in[1];
    const float* ea      = (const float*)d_in[2];
    const int*   eidx    = (const int*)d_in[3];
    const int*   batch   = (const int*)d_in[4];
    const float* W_embed = (const float*)d_in[5];
    const float* b_embed = (const float*)d_in[6];
    const float* W_ee    = (const float*)d_in[7];
    const float* b_ee    = (const float*)d_in[8];
    const float* Wm      = (const float*)d_in[9];
    const float* bm      = (const float*)d_in[10];
    const float* Wh      = (const float*)d_in[11];
    const float* bh      = (const float*)d_in[12];
    const float* We      = (const float*)d_in[13];
    const float* be      = (const float*)d_in[14];
    const int* send = eidx;
    const int* rec  = eidx + NE;

    // ---- workspace layout (all chunks multiples of 16B) ----
    char* w = (char*)d_ws;
    const size_t NHb = (size_t)NN * 128 * sizeof(u16);     // 12.8 MB
    u16* hA  = (u16*)w; w += NHb;
    u16* hB  = (u16*)w; w += NHb;
    u16* dhA = (u16*)w; w += NHb;
    u16* dhB = (u16*)w; w += NHb;
    u16* SeA = (u16*)w; w += NHb;
    u16* SeB = (u16*)w; w += NHb;
    u16* Sh  = (u16*)w; w += NHb;
    float* Sea   = (float*)w; w += (size_t)NN * 16 * 4;    // 3.2 MB
    int*  deg    = (int*)w;   w += (size_t)NN * 4;
    int*  offs   = (int*)w;   w += (size_t)(NN + 4) * 4;   // pad to 16B
    int*  cursor = (int*)w;   w += (size_t)NN * 4;
    int*  csr    = (int*)w;   w += (size_t)NE * 4;
    float* Wb    = (float*)w; w += (size_t)4 * 512 * 256 * 4;
    float* cvec  = (float*)w; w += 512 * 4;
    u16*  Bp     = (u16*)w;   w += (size_t)4 * 512 * 256 * 2;
    const size_t need = (size_t)(w - (char*)d_ws);
    if (ws_size < need) {
        fprintf(stderr, "[kernel_launch] ws_size=%zu < needed=%zu — skipping\n",
                ws_size, need);
        return;
    }

    float* out = (float*)d_out;

    hipMemsetAsync(d_out, 0, (size_t)NG * 128 * sizeof(float), stream);
    hipMemsetAsync(Sea, 0, ((size_t)NN * 16 + NN) * sizeof(float), stream); // Sea + deg

    k_deg_sea<<<NE / 16, 256, 0, stream>>>(ea, rec, Sea, deg);
    k_node_embed<<<NN / 2, 256, 0, stream>>>(x, p, W_embed, b_embed, hA);
    k_se0<<<NN / 2, 256, 0, stream>>>(Sea, deg, W_ee, b_ee, SeA);
    k_dh0<<<NN * 64 / 256, 256, 0, stream>>>(hA, deg, dhA);
    k_wprep<<<(4 * 512 * 256 + 512 + 255) / 256, 256, 0, stream>>>(Wm, Wh, We, bm, Wb, cvec);
    k_wswz<<<4 * 512 * 256 / 256, 256, 0, stream>>>(Wb, Bp);
    k_scan<<<1, 256, 0, stream>>>(deg, offs, cursor);
    k_fill<<<NE / 256, 256, 0, stream>>>(send, rec, cursor, csr);

    u16* h_cur = hA;   u16* h_nxt = hB;
    u16* dh_cur = dhA; u16* dh_nxt = dhB;
    u16* Se_cur = SeA; u16* Se_nxt = SeB;
    for (int l = 0; l < NL; ++l) {
        k_gather<<<NN / 4, 256, 0, stream>>>(h_cur, csr, offs, deg, Sh);
        k_dense<<<(NN + 63) / 64, 256, 0, stream>>>(h_cur, dh_cur, Sh, Se_cur,
            deg, Bp + (size_t)l * 512 * 256,
            cvec + l * 128, bh + l * 128, be + l * 128,
            h_nxt, dh_nxt, Se_nxt);
        u16* tmp;
        tmp = h_cur;  h_cur  = h_nxt;  h_nxt  = tmp;
        tmp = dh_cur; dh_cur = dh_nxt; dh_nxt = tmp;
        tmp = Se_cur; Se_cur = Se_nxt; Se_nxt = tmp;
    }
    k_pool<<<(NN + 63) / 64, 256, 0, stream>>>(h_cur, batch, out);
}

// Round 5
// 603.840 us; speedup vs baseline: 15.4054x; 1.2041x over previous
//
#include <hip/hip_runtime.h>
#include <cstdio>

#define NN 50000
#define NE 640000
#define NG 256
#define NL 4

#define SCAN_CHUNK 1024
#define NB_SCAN ((NN + SCAN_CHUNK - 1) / SCAN_CHUNK)   // 49

typedef unsigned short u16;
typedef unsigned int u32;
typedef __attribute__((ext_vector_type(8))) short short8v;   // 8 bf16 = 4 VGPR
typedef __attribute__((ext_vector_type(4))) float f32x4;

static __device__ __forceinline__ float bf2f(u16 v) {
    return __uint_as_float(((u32)v) << 16);
}
static __device__ __forceinline__ u16 f2bf(float f) {
    u32 u = __float_as_uint(f);
    u += 0x7fff + ((u >> 16) & 1);   // RNE
    return (u16)(u >> 16);
}

// ---------------- k_deg_sea: deg(int) histogram + Sea = segsum(e_attr, rec) ----------------
__global__ __launch_bounds__(256) void k_deg_sea(
    const float* __restrict__ ea, const int* __restrict__ rec,
    float* __restrict__ Sea, int* __restrict__ deg)
{
    const int t = threadIdx.x;
    const int e = blockIdx.x * 16 + (t >> 4);
    const int c = t & 15;
    const int r = rec[e];
    atomicAdd(&Sea[(size_t)r * 16 + c], ea[(size_t)e * 16 + c]);
    if (c == 0) atomicAdd(&deg[r], 1);
}

// ---------------- k_node_embed: h0 = cat(x,p) @ W_embed + b  (bf16 out, + dh) ----------------
__global__ __launch_bounds__(256) void k_node_embed(
    const float* __restrict__ x, const float* __restrict__ p,
    const float* __restrict__ W, const float* __restrict__ b,
    const int* __restrict__ deg,
    u16* __restrict__ h, u16* __restrict__ dh)
{
    __shared__ float row[2][80];
    const int t = threadIdx.x;
    const int nl = t >> 7;
    const int col = t & 127;
    const int node = blockIdx.x * 2 + nl;
    if (col < 64)       row[nl][col] = x[node * 64 + col];
    else if (col < 80)  row[nl][col] = p[node * 16 + (col - 64)];
    __syncthreads();
    float acc = b[col];
    #pragma unroll 8
    for (int k = 0; k < 80; ++k) acc += row[nl][k] * W[k * 128 + col];
    const float hv = bf2f(f2bf(acc));
    h[(size_t)node * 128 + col]  = f2bf(acc);
    dh[(size_t)node * 128 + col] = f2bf(hv * (float)deg[node]);
}

// ---------------- k_se0: Se0 = Sea @ W_ee + deg * b_ee  (bf16 out) ----------------
__global__ __launch_bounds__(256) void k_se0(
    const float* __restrict__ Sea, const int* __restrict__ deg,
    const float* __restrict__ Wee, const float* __restrict__ bee,
    u16* __restrict__ Se)
{
    __shared__ float row[2][16];
    const int t = threadIdx.x;
    const int nl = t >> 7;
    const int col = t & 127;
    const int node = blockIdx.x * 2 + nl;
    if (col < 16) row[nl][col] = Sea[(size_t)node * 16 + col];
    __syncthreads();
    float acc = (float)deg[node] * bee[col];
    #pragma unroll
    for (int k = 0; k < 16; ++k) acc += row[nl][k] * Wee[k * 128 + col];
    Se[(size_t)node * 128 + col] = f2bf(acc);
}

// ---------------- k_wprep: build Wb fp32 [l][512][256] + cvec ----------------
// A rows = [h | dh | Sh | Se];
// cols 0:128 (h'):  [Wh1 ; Wm2@Wh2 ; Wm1@Wh2 ; Wm3@Wh2]; cols 128:256 (Se'): [0 ; We2 ; We1 ; We3]
__global__ __launch_bounds__(256) void k_wprep(
    const float* __restrict__ Wm, const float* __restrict__ Wh,
    const float* __restrict__ We, const float* __restrict__ bm,
    float* __restrict__ Wb, float* __restrict__ cvec)
{
    const int idx = blockIdx.x * 256 + threadIdx.x;
    const int total = 4 * 512 * 256;
    if (idx < total) {
        const int l = idx >> 17;
        const int rem = idx & 131071;
        const int k = rem >> 8;
        const int c = rem & 255;
        const float* Wm_l = Wm + (size_t)l * 384 * 128;
        const float* Wh_l = Wh + (size_t)l * 256 * 128;
        const float* We_l = We + (size_t)l * 384 * 128;
        float v;
        if (k < 128) {
            v = (c < 128) ? Wh_l[k * 128 + c] : 0.f;
        } else {
            const int kk  = (k - 128) & 127;
            const int blk = (k - 128) >> 7;               // 0:dh 1:Sh 2:Se
            const int roff = (blk == 0) ? 128 : (blk == 1) ? 0 : 256;
            if (c < 128) {
                float s = 0.f;
                #pragma unroll 4
                for (int j = 0; j < 128; ++j)
                    s += Wm_l[(roff + kk) * 128 + j] * Wh_l[(128 + j) * 128 + c];
                v = s;
            } else {
                v = We_l[(roff + kk) * 128 + (c - 128)];
            }
        }
        Wb[idx] = v;
    } else if (idx < total + 512) {
        const int r = idx - total;
        const int l = r >> 7;
        const int c = r & 127;
        const float* Wh_l = Wh + (size_t)l * 256 * 128;
        const float* bm_l = bm + l * 128;
        float s = 0.f;
        #pragma unroll 4
        for (int j = 0; j < 128; ++j) s += bm_l[j] * Wh_l[(128 + j) * 128 + c];
        cvec[r] = s;
    }
}

// ---------------- k_wswz: Wb fp32 -> Bp bf16 swizzled [l][k>>5][n][k&31] ----------------
__global__ __launch_bounds__(256) void k_wswz(
    const float* __restrict__ Wb, u16* __restrict__ Bp)
{
    const int idx = blockIdx.x * 256 + threadIdx.x;    // 4*512*256
    const int l = idx >> 17;
    const int rem = idx & 131071;
    const int k = rem >> 8;
    const int n = rem & 255;
    Bp[(((size_t)l * 16 + (k >> 5)) * 256 + n) * 32 + (k & 31)] = f2bf(Wb[idx]);
}

// ---------------- parallel exclusive scan of deg (3 phases) ----------------
__global__ __launch_bounds__(256) void k_scanA(
    const int* __restrict__ deg, int* __restrict__ part)
{
    __shared__ int red[256];
    const int t = threadIdx.x;
    const int base = blockIdx.x * SCAN_CHUNK + t * 4;
    int s = 0;
    #pragma unroll
    for (int i = 0; i < 4; ++i) {
        const int idx = base + i;
        if (idx < NN) s += deg[idx];
    }
    red[t] = s;
    __syncthreads();
    for (int off = 128; off > 0; off >>= 1) {
        if (t < off) red[t] += red[t + off];
        __syncthreads();
    }
    if (t == 0) part[blockIdx.x] = red[0];
}

__global__ __launch_bounds__(64) void k_scanB(int* part)   // in-place -> exclusive
{
    if (threadIdx.x == 0) {
        int run = 0;
        for (int b = 0; b < NB_SCAN; ++b) {
            const int v = part[b];
            part[b] = run;
            run += v;
        }
    }
}

__global__ __launch_bounds__(256) void k_scanC(
    const int* __restrict__ deg, const int* __restrict__ part,
    int* __restrict__ offs, int* __restrict__ cursor)
{
    __shared__ int ts[256];
    const int t = threadIdx.x;
    const int base = blockIdx.x * SCAN_CHUNK + t * 4;
    int v[4]; int s = 0;
    #pragma unroll
    for (int i = 0; i < 4; ++i) {
        const int idx = base + i;
        v[i] = (idx < NN) ? deg[idx] : 0;
        s += v[i];
    }
    ts[t] = s;
    __syncthreads();
    for (int off = 1; off < 256; off <<= 1) {
        int val = ts[t];
        if (t >= off) val += ts[t - off];
        __syncthreads();
        ts[t] = val;
        __syncthreads();
    }
    int run = part[blockIdx.x] + ((t == 0) ? 0 : ts[t - 1]);
    #pragma unroll
    for (int i = 0; i < 4; ++i) {
        const int idx = base + i;
        if (idx < NN) { offs[idx] = run; cursor[idx] = run; run += v[i]; }
    }
}

// ---------------- k_fill: csr[pos] = send, pos by atomic cursor per receiver ----------------
__global__ __launch_bounds__(256) void k_fill(
    const int* __restrict__ send, const int* __restrict__ rec,
    int* __restrict__ cursor, int* __restrict__ csr)
{
    const int e = blockIdx.x * 256 + threadIdx.x;
    const int r = rec[e];
    const int pos = atomicAdd(&cursor[r], 1);
    csr[pos] = send[e];
}

// ---------------- k_gather: Sh[n] = sum over incoming edges of h[send] (no atomics) ----------------
__global__ __launch_bounds__(256) void k_gather(
    const u16* __restrict__ h, const int* __restrict__ csr,
    const int* __restrict__ offs, const int* __restrict__ deg,
    u16* __restrict__ Sh)
{
    const int t = threadIdx.x;
    const int lane = t & 63;
    const int node = blockIdx.x * 4 + (t >> 6);     // grid 12500*4 = NN exact
    const int off = offs[node];
    const int d = deg[node];
    const u32* hp = (const u32*)h;
    float a0 = 0.f, a1 = 0.f, b0 = 0.f, b1 = 0.f;
    int j = 0;
    for (; j + 2 <= d; j += 2) {
        const int s0 = csr[off + j];
        const int s1 = csr[off + j + 1];
        const u32 v0 = hp[(size_t)s0 * 64 + lane];
        const u32 v1 = hp[(size_t)s1 * 64 + lane];
        a0 += bf2f((u16)(v0 & 0xffff)); a1 += bf2f((u16)(v0 >> 16));
        b0 += bf2f((u16)(v1 & 0xffff)); b1 += bf2f((u16)(v1 >> 16));
    }
    if (j < d) {
        const u32 v0 = hp[(size_t)csr[off + j] * 64 + lane];
        a0 += bf2f((u16)(v0 & 0xffff)); a1 += bf2f((u16)(v0 >> 16));
    }
    a0 += b0; a1 += b1;
    ((u32*)Sh)[(size_t)node * 64 + lane] = (u32)f2bf(a0) | ((u32)f2bf(a1) << 16);
}

// ---------------- k_dense: [h|dh|Sh|Se] @ Wb via bf16 MFMA ----------------
// block = 4 waves; wave (wm,wn): rows rb..rb+31 (2 m-frags), cols wn*128..+127 (8 n-frags).
// FULL=false (last layer): Se'/dh' not needed -> wn==1 waves exit, no dh_out write.
template<bool FULL>
__global__ __launch_bounds__(256) void k_dense(
    const u16* __restrict__ h, const u16* __restrict__ dh,
    const u16* __restrict__ Sh, const u16* __restrict__ Se,
    const int* __restrict__ deg, const u16* __restrict__ Bp,
    const float* __restrict__ cvec, const float* __restrict__ bh,
    const float* __restrict__ be,
    u16* __restrict__ h_out, u16* __restrict__ dh_out, u16* __restrict__ Se_out)
{
    const int t = threadIdx.x;
    const int lane = t & 63;
    const int w = t >> 6;
    const int wm = w & 1;
    const int wn = w >> 1;
    if (!FULL && wn == 1) return;
    const int rb = blockIdx.x * 64 + wm * 32;
    const int cb = wn * 128;
    const int l15 = lane & 15;
    const int kg  = lane >> 4;

    int r0 = rb + l15;      if (r0 > NN - 1) r0 = NN - 1;
    int r1 = rb + 16 + l15; if (r1 > NN - 1) r1 = NN - 1;
    const size_t a0off = (size_t)r0 * 128 + kg * 8;
    const size_t a1off = (size_t)r1 * 128 + kg * 8;

    f32x4 acc[2][8];
    #pragma unroll
    for (int m = 0; m < 2; ++m)
        #pragma unroll
        for (int n = 0; n < 8; ++n) acc[m][n] = (f32x4){0.f, 0.f, 0.f, 0.f};

    #pragma unroll
    for (int s = 0; s < 4; ++s) {
        const u16* __restrict__ Sp = (s == 0) ? h : (s == 1) ? dh : (s == 2) ? Sh : Se;
        #pragma unroll
        for (int k4 = 0; k4 < 4; ++k4) {
            const int ks = s * 4 + k4;     // 0..15
            const short8v a0 = *(const short8v*)(Sp + a0off + k4 * 32);
            const short8v a1 = *(const short8v*)(Sp + a1off + k4 * 32);
            const u16* bb = Bp + (((size_t)ks * 256) + cb + l15) * 32 + kg * 8;
            #pragma unroll
            for (int nf = 0; nf < 8; ++nf) {
                const short8v b = *(const short8v*)(bb + (size_t)nf * 16 * 32);
                acc[0][nf] = __builtin_amdgcn_mfma_f32_16x16x32_bf16(a0, b, acc[0][nf], 0, 0, 0);
                acc[1][nf] = __builtin_amdgcn_mfma_f32_16x16x32_bf16(a1, b, acc[1][nf], 0, 0, 0);
            }
        }
    }

    #pragma unroll
    for (int m = 0; m < 2; ++m) {
        #pragma unroll
        for (int r = 0; r < 4; ++r) {
            const int row = rb + m * 16 + kg * 4 + r;
            if (row < NN) {
                const float dg = (float)deg[row];
                if (cb == 0) {
                    #pragma unroll
                    for (int nf = 0; nf < 8; ++nf) {
                        const int col = nf * 16 + l15;
                        const float v = acc[m][nf][r] + bh[col] + dg * cvec[col];
                        h_out[(size_t)row * 128 + col] = f2bf(v);
                        if (FULL)
                            dh_out[(size_t)row * 128 + col] = f2bf(bf2f(f2bf(v)) * dg);
                    }
                } else {
                    #pragma unroll
                    for (int nf = 0; nf < 8; ++nf) {
                        const int col = nf * 16 + l15;
                        const float v = acc[m][nf][r] + dg * be[col];
                        Se_out[(size_t)row * 128 + col] = f2bf(v);
                    }
                }
            }
        }
    }
}

// ---------------- k_pool ----------------
__global__ __launch_bounds__(256) void k_pool(
    const u16* __restrict__ h, const int* __restrict__ batch,
    float* __restrict__ out)
{
    const int t = threadIdx.x;
    const int col = t & 127;
    const int half = t >> 7;
    const int base = blockIdx.x * 64 + half * 32;
    float acc = 0.f;
    int curg = -1;
    for (int i = 0; i < 32; ++i) {
        const int n = base + i;
        if (n >= NN) break;
        const int g = batch[n];
        if (g != curg) {
            if (curg >= 0) atomicAdd(&out[curg * 128 + col], acc);
            curg = g; acc = 0.f;
        }
        acc += bf2f(h[(size_t)n * 128 + col]);
    }
    if (curg >= 0) atomicAdd(&out[curg * 128 + col], acc);
}

extern "C" void kernel_launch(void* const* d_in, const int* in_sizes, int n_in,
                              void* d_out, int out_size, void* d_ws, size_t ws_size,
                              hipStream_t stream)
{
    const float* x       = (const float*)d_in[0];
    const float* p       = (const float*)d_in[1];
    const float* ea      = (const float*)d_in[2];
    const int*   eidx    = (const int*)d_in[3];
    const int*   batch   = (const int*)d_in[4];
    const float* W_embed = (const float*)d_in[5];
    const float* b_embed = (const float*)d_in[6];
    const float* W_ee    = (const float*)d_in[7];
    const float* b_ee    = (const float*)d_in[8];
    const float* Wm      = (const float*)d_in[9];
    const float* bm      = (const float*)d_in[10];
    const float* Wh      = (const float*)d_in[11];
    const float* bh      = (const float*)d_in[12];
    const float* We      = (const float*)d_in[13];
    const float* be      = (const float*)d_in[14];
    const int* send = eidx;
    const int* rec  = eidx + NE;

    // ---- workspace layout (all chunks multiples of 16B) ----
    char* w = (char*)d_ws;
    const size_t NHb = (size_t)NN * 128 * sizeof(u16);     // 12.8 MB
    u16* hA  = (u16*)w; w += NHb;
    u16* hB  = (u16*)w; w += NHb;
    u16* dhA = (u16*)w; w += NHb;
    u16* dhB = (u16*)w; w += NHb;
    u16* SeA = (u16*)w; w += NHb;
    u16* SeB = (u16*)w; w += NHb;
    u16* Sh  = (u16*)w; w += NHb;
    float* Sea   = (float*)w; w += (size_t)NN * 16 * 4;    // 3.2 MB
    int*  deg    = (int*)w;   w += (size_t)NN * 4;
    int*  offs   = (int*)w;   w += (size_t)(NN + 4) * 4;   // pad to 16B
    int*  cursor = (int*)w;   w += (size_t)NN * 4;
    int*  csr    = (int*)w;   w += (size_t)NE * 4;
    int*  part   = (int*)w;   w += 64 * 4;                 // NB_SCAN=49, padded
    float* Wb    = (float*)w; w += (size_t)4 * 512 * 256 * 4;
    float* cvec  = (float*)w; w += 512 * 4;
    u16*  Bp     = (u16*)w;   w += (size_t)4 * 512 * 256 * 2;
    const size_t need = (size_t)(w - (char*)d_ws);
    if (ws_size < need) {
        fprintf(stderr, "[kernel_launch] ws_size=%zu < needed=%zu — skipping\n",
                ws_size, need);
        return;
    }

    float* out = (float*)d_out;

    hipMemsetAsync(d_out, 0, (size_t)NG * 128 * sizeof(float), stream);
    hipMemsetAsync(Sea, 0, ((size_t)NN * 16 + NN) * sizeof(float), stream); // Sea + deg

    k_deg_sea<<<NE / 16, 256, 0, stream>>>(ea, rec, Sea, deg);
    k_node_embed<<<NN / 2, 256, 0, stream>>>(x, p, W_embed, b_embed, deg, hA, dhA);
    k_se0<<<NN / 2, 256, 0, stream>>>(Sea, deg, W_ee, b_ee, SeA);
    k_wprep<<<(4 * 512 * 256 + 512 + 255) / 256, 256, 0, stream>>>(Wm, Wh, We, bm, Wb, cvec);
    k_wswz<<<4 * 512 * 256 / 256, 256, 0, stream>>>(Wb, Bp);
    k_scanA<<<NB_SCAN, 256, 0, stream>>>(deg, part);
    k_scanB<<<1, 64, 0, stream>>>(part);
    k_scanC<<<NB_SCAN, 256, 0, stream>>>(deg, part, offs, cursor);
    k_fill<<<NE / 256, 256, 0, stream>>>(send, rec, cursor, csr);

    u16* h_cur = hA;   u16* h_nxt = hB;
    u16* dh_cur = dhA; u16* dh_nxt = dhB;
    u16* Se_cur = SeA; u16* Se_nxt = SeB;
    for (int l = 0; l < NL; ++l) {
        k_gather<<<NN / 4, 256, 0, stream>>>(h_cur, csr, offs, deg, Sh);
        if (l < NL - 1)
            k_dense<true><<<(NN + 63) / 64, 256, 0, stream>>>(h_cur, dh_cur, Sh, Se_cur,
                deg, Bp + (size_t)l * 512 * 256,
                cvec + l * 128, bh + l * 128, be + l * 128,
                h_nxt, dh_nxt, Se_nxt);
        else
            k_dense<false><<<(NN + 63) / 64, 256, 0, stream>>>(h_cur, dh_cur, Sh, Se_cur,
                deg, Bp + (size_t)l * 512 * 256,
                cvec + l * 128, bh + l * 128, be + l * 128,
                h_nxt, dh_nxt, Se_nxt);
        u16* tmp;
        tmp = h_cur;  h_cur  = h_nxt;  h_nxt  = tmp;
        tmp = dh_cur; dh_cur = dh_nxt; dh_nxt = tmp;
        tmp = Se_cur; Se_cur = Se_nxt; Se_nxt = tmp;
    }
    k_pool<<<(NN + 63) / 64, 256, 0, stream>>>(h_cur, batch, out);
}

// Round 6
// 520.876 us; speedup vs baseline: 17.8591x; 1.1593x over previous
//
#include <hip/hip_runtime.h>
#include <cstdio>

#define NN 50000
#define NE 640000
#define NG 256
#define NL 4

#define SCAN_CHUNK 1024
#define NB_SCAN ((NN + SCAN_CHUNK - 1) / SCAN_CHUNK)   // 49

typedef unsigned short u16;
typedef unsigned int u32;
typedef __attribute__((ext_vector_type(8))) short short8v;   // 8 bf16 = 4 VGPR
typedef __attribute__((ext_vector_type(4))) float f32x4;

static __device__ __forceinline__ float bf2f(u16 v) {
    return __uint_as_float(((u32)v) << 16);
}
static __device__ __forceinline__ u16 f2bf(float f) {
    u32 u = __float_as_uint(f);
    u += 0x7fff + ((u >> 16) & 1);   // RNE
    return (u16)(u >> 16);
}

// ---------------- k_deg: deg histogram ----------------
__global__ __launch_bounds__(256) void k_deg(
    const int* __restrict__ rec, int* __restrict__ deg)
{
    const int e = blockIdx.x * 256 + threadIdx.x;
    atomicAdd(&deg[rec[e]], 1);
}

// ---------------- k_prep_xp: Axp bf16 [NN][96] = cat(x,p) zero-padded ----------------
__global__ __launch_bounds__(256) void k_prep_xp(
    const float* __restrict__ x, const float* __restrict__ p,
    u16* __restrict__ Axp)
{
    const int idx = blockIdx.x * 256 + threadIdx.x;   // NN*48 u32s
    const int row = idx / 48;
    const int c2 = idx - row * 48;
    const int c0 = c2 * 2;
    float f0, f1;
    if (c0 < 64)      { f0 = x[(size_t)row * 64 + c0]; f1 = x[(size_t)row * 64 + c0 + 1]; }
    else if (c0 < 80) { f0 = p[(size_t)row * 16 + c0 - 64]; f1 = p[(size_t)row * 16 + c0 - 63]; }
    else              { f0 = 0.f; f1 = 0.f; }
    ((u32*)Axp)[idx] = (u32)f2bf(f0) | ((u32)f2bf(f1) << 16);
}

// ---------------- k_wembed: W_embed -> bf16 swizzled [ks][col][32] (K pad 96) ----------------
__global__ __launch_bounds__(256) void k_wembed(
    const float* __restrict__ W, u16* __restrict__ Wp)
{
    const int idx = blockIdx.x * 256 + threadIdx.x;   // 3*128*32
    const int ks = idx >> 12;
    const int rem = idx & 4095;
    const int col = rem >> 5;
    const int kk = rem & 31;
    const int k = ks * 32 + kk;
    Wp[((size_t)ks * 128 + col) * 32 + kk] = f2bf(k < 80 ? W[k * 128 + col] : 0.f);
}

// ---------------- k_embed: h0/dh0 via MFMA  [NN,96]@[96,128] ----------------
__global__ __launch_bounds__(256) void k_embed(
    const u16* __restrict__ Axp, const u16* __restrict__ Wp,
    const float* __restrict__ b, const int* __restrict__ deg,
    u16* __restrict__ h, u16* __restrict__ dh)
{
    const int t = threadIdx.x;
    const int lane = t & 63;
    const int w = t >> 6;
    const int rb = blockIdx.x * 128 + w * 32;
    const int l15 = lane & 15;
    const int kg  = lane >> 4;

    int r0 = rb + l15;      if (r0 > NN - 1) r0 = NN - 1;
    int r1 = rb + 16 + l15; if (r1 > NN - 1) r1 = NN - 1;

    f32x4 acc[2][8];
    #pragma unroll
    for (int m = 0; m < 2; ++m)
        #pragma unroll
        for (int n = 0; n < 8; ++n) acc[m][n] = (f32x4){0.f, 0.f, 0.f, 0.f};

    #pragma unroll
    for (int ks = 0; ks < 3; ++ks) {
        const short8v a0 = *(const short8v*)(Axp + (size_t)r0 * 96 + ks * 32 + kg * 8);
        const short8v a1 = *(const short8v*)(Axp + (size_t)r1 * 96 + ks * 32 + kg * 8);
        const u16* bb = Wp + ((size_t)ks * 128 + l15) * 32 + kg * 8;
        #pragma unroll
        for (int nf = 0; nf < 8; ++nf) {
            const short8v bv = *(const short8v*)(bb + (size_t)nf * 16 * 32);
            acc[0][nf] = __builtin_amdgcn_mfma_f32_16x16x32_bf16(a0, bv, acc[0][nf], 0, 0, 0);
            acc[1][nf] = __builtin_amdgcn_mfma_f32_16x16x32_bf16(a1, bv, acc[1][nf], 0, 0, 0);
        }
    }

    #pragma unroll
    for (int m = 0; m < 2; ++m) {
        #pragma unroll
        for (int r = 0; r < 4; ++r) {
            const int row = rb + m * 16 + kg * 4 + r;
            if (row < NN) {
                const float dg = (float)deg[row];
                #pragma unroll
                for (int nf = 0; nf < 8; ++nf) {
                    const int col = nf * 16 + l15;
                    const float v = acc[m][nf][r] + b[col];
                    h[(size_t)row * 128 + col]  = f2bf(v);
                    dh[(size_t)row * 128 + col] = f2bf(bf2f(f2bf(v)) * dg);
                }
            }
        }
    }
}

// ---------------- k_wprep: build Wb fp32 [l][512][256] + cvec ----------------
__global__ __launch_bounds__(256) void k_wprep(
    const float* __restrict__ Wm, const float* __restrict__ Wh,
    const float* __restrict__ We, const float* __restrict__ bm,
    float* __restrict__ Wb, float* __restrict__ cvec)
{
    const int idx = blockIdx.x * 256 + threadIdx.x;
    const int total = 4 * 512 * 256;
    if (idx < total) {
        const int l = idx >> 17;
        const int rem = idx & 131071;
        const int k = rem >> 8;
        const int c = rem & 255;
        const float* Wm_l = Wm + (size_t)l * 384 * 128;
        const float* Wh_l = Wh + (size_t)l * 256 * 128;
        const float* We_l = We + (size_t)l * 384 * 128;
        float v;
        if (k < 128) {
            v = (c < 128) ? Wh_l[k * 128 + c] : 0.f;
        } else {
            const int kk  = (k - 128) & 127;
            const int blk = (k - 128) >> 7;               // 0:dh 1:Sh 2:Se
            const int roff = (blk == 0) ? 128 : (blk == 1) ? 0 : 256;
            if (c < 128) {
                float s = 0.f;
                #pragma unroll 4
                for (int j = 0; j < 128; ++j)
                    s += Wm_l[(roff + kk) * 128 + j] * Wh_l[(128 + j) * 128 + c];
                v = s;
            } else {
                v = We_l[(roff + kk) * 128 + (c - 128)];
            }
        }
        Wb[idx] = v;
    } else if (idx < total + 512) {
        const int r = idx - total;
        const int l = r >> 7;
        const int c = r & 127;
        const float* Wh_l = Wh + (size_t)l * 256 * 128;
        const float* bm_l = bm + l * 128;
        float s = 0.f;
        #pragma unroll 4
        for (int j = 0; j < 128; ++j) s += bm_l[j] * Wh_l[(128 + j) * 128 + c];
        cvec[r] = s;
    }
}

// ---------------- k_wswz: Wb fp32 -> Bp bf16 swizzled [l][k>>5][n][k&31] ----------------
__global__ __launch_bounds__(256) void k_wswz(
    const float* __restrict__ Wb, u16* __restrict__ Bp)
{
    const int idx = blockIdx.x * 256 + threadIdx.x;    // 4*512*256
    const int l = idx >> 17;
    const int rem = idx & 131071;
    const int k = rem >> 8;
    const int n = rem & 255;
    Bp[(((size_t)l * 16 + (k >> 5)) * 256 + n) * 32 + (k & 31)] = f2bf(Wb[idx]);
}

// ---------------- parallel exclusive scan of deg (3 phases) ----------------
__global__ __launch_bounds__(256) void k_scanA(
    const int* __restrict__ deg, int* __restrict__ part)
{
    __shared__ int red[256];
    const int t = threadIdx.x;
    const int base = blockIdx.x * SCAN_CHUNK + t * 4;
    int s = 0;
    #pragma unroll
    for (int i = 0; i < 4; ++i) {
        const int idx = base + i;
        if (idx < NN) s += deg[idx];
    }
    red[t] = s;
    __syncthreads();
    for (int off = 128; off > 0; off >>= 1) {
        if (t < off) red[t] += red[t + off];
        __syncthreads();
    }
    if (t == 0) part[blockIdx.x] = red[0];
}

__global__ __launch_bounds__(64) void k_scanB(int* part)   // in-place -> exclusive
{
    if (threadIdx.x == 0) {
        int run = 0;
        for (int b = 0; b < NB_SCAN; ++b) {
            const int v = part[b];
            part[b] = run;
            run += v;
        }
    }
}

__global__ __launch_bounds__(256) void k_scanC(
    const int* __restrict__ deg, const int* __restrict__ part,
    int* __restrict__ offs, int* __restrict__ cursor)
{
    __shared__ int ts[256];
    const int t = threadIdx.x;
    const int base = blockIdx.x * SCAN_CHUNK + t * 4;
    int v[4]; int s = 0;
    #pragma unroll
    for (int i = 0; i < 4; ++i) {
        const int idx = base + i;
        v[i] = (idx < NN) ? deg[idx] : 0;
        s += v[i];
    }
    ts[t] = s;
    __syncthreads();
    for (int off = 1; off < 256; off <<= 1) {
        int val = ts[t];
        if (t >= off) val += ts[t - off];
        __syncthreads();
        ts[t] = val;
        __syncthreads();
    }
    int run = part[blockIdx.x] + ((t == 0) ? 0 : ts[t - 1]);
    #pragma unroll
    for (int i = 0; i < 4; ++i) {
        const int idx = base + i;
        if (idx < NN) { offs[idx] = run; cursor[idx] = run; run += v[i]; }
    }
}

// ---------------- k_fill: csr[pos]=send, csr_e[pos]=edge ----------------
__global__ __launch_bounds__(256) void k_fill(
    const int* __restrict__ send, const int* __restrict__ rec,
    int* __restrict__ cursor, int* __restrict__ csr, int* __restrict__ csr_e)
{
    const int e = blockIdx.x * 256 + threadIdx.x;
    const int r = rec[e];
    const int pos = atomicAdd(&cursor[r], 1);
    csr[pos] = send[e];
    csr_e[pos] = e;
}

// ---------------- k_sea_se0: Sea gather (CSR) fused with Se0 GEMM ----------------
// 4 nodes per block (1 per wave). Gather: group g=lane>>4 takes edge j+g,
// 16 lanes read the 64B ea row. Reduce across groups via shfl_xor. Then
// Se0 = sea @ Wee + deg*bee computed block-wide.
__global__ __launch_bounds__(256) void k_sea_se0(
    const float* __restrict__ ea, const int* __restrict__ csr_e,
    const int* __restrict__ offs, const int* __restrict__ deg,
    const float* __restrict__ Wee, const float* __restrict__ bee,
    u16* __restrict__ Se)
{
    __shared__ float sea[4][16];
    const int t = threadIdx.x;
    const int lane = t & 63;
    const int w = t >> 6;
    const int nb = blockIdx.x * 4;
    const int node = nb + w;
    const int g = lane >> 4;
    const int l16 = lane & 15;
    const int off = offs[node];
    const int d = deg[node];

    float acc = 0.f;
    for (int j = 0; j < d; j += 4) {
        const int jj = j + g;
        if (jj < d) {
            const int eid = csr_e[off + jj];
            acc += ea[(size_t)eid * 16 + l16];
        }
    }
    acc += __shfl_xor(acc, 16);
    acc += __shfl_xor(acc, 32);
    if (g == 0) sea[w][l16] = acc;
    __syncthreads();

    const int c = t & 127;
    #pragma unroll
    for (int q = 0; q < 2; ++q) {
        const int n = (t >> 7) + 2 * q;
        const int nd = nb + n;
        float a = (float)deg[nd] * bee[c];
        #pragma unroll
        for (int k = 0; k < 16; ++k) a += sea[n][k] * Wee[k * 128 + c];
        Se[(size_t)nd * 128 + c] = f2bf(a);
    }
}

// ---------------- k_gather: Sh[n] = sum of h[send] over incoming edges ----------------
// 1 node per wave; 4 edges in flight (group g), 16B/lane loads; shfl reduce.
__global__ __launch_bounds__(256) void k_gather(
    const u16* __restrict__ h, const int* __restrict__ csr,
    const int* __restrict__ offs, const int* __restrict__ deg,
    u16* __restrict__ Sh)
{
    const int t = threadIdx.x;
    const int lane = t & 63;
    const int node = blockIdx.x * 4 + (t >> 6);     // grid 12500*4 = NN exact
    const int g = lane >> 4;
    const int l16 = lane & 15;
    const int off = offs[node];
    const int d = deg[node];
    const uint4* hp = (const uint4*)h;

    float acc[8];
    #pragma unroll
    for (int i = 0; i < 8; ++i) acc[i] = 0.f;

    for (int j = 0; j < d; j += 4) {
        const int jj = j + g;
        if (jj < d) {
            const int s = csr[off + jj];
            const uint4 v = hp[(size_t)s * 16 + l16];
            acc[0] += bf2f((u16)(v.x & 0xffff)); acc[1] += bf2f((u16)(v.x >> 16));
            acc[2] += bf2f((u16)(v.y & 0xffff)); acc[3] += bf2f((u16)(v.y >> 16));
            acc[4] += bf2f((u16)(v.z & 0xffff)); acc[5] += bf2f((u16)(v.z >> 16));
            acc[6] += bf2f((u16)(v.w & 0xffff)); acc[7] += bf2f((u16)(v.w >> 16));
        }
    }
    #pragma unroll
    for (int i = 0; i < 8; ++i) {
        float s = acc[i];
        s += __shfl_xor(s, 16);
        s += __shfl_xor(s, 32);
        acc[i] = s;
    }
    if (g == 0) {
        uint4 o;
        o.x = (u32)f2bf(acc[0]) | ((u32)f2bf(acc[1]) << 16);
        o.y = (u32)f2bf(acc[2]) | ((u32)f2bf(acc[3]) << 16);
        o.z = (u32)f2bf(acc[4]) | ((u32)f2bf(acc[5]) << 16);
        o.w = (u32)f2bf(acc[6]) | ((u32)f2bf(acc[7]) << 16);
        ((uint4*)Sh)[(size_t)node * 16 + l16] = o;
    }
}

// ---------------- k_dense: [h|dh|Sh|Se] @ Wb via bf16 MFMA ----------------
template<bool FULL>
__global__ __launch_bounds__(256) void k_dense(
    const u16* __restrict__ h, const u16* __restrict__ dh,
    const u16* __restrict__ Sh, const u16* __restrict__ Se,
    const int* __restrict__ deg, const u16* __restrict__ Bp,
    const float* __restrict__ cvec, const float* __restrict__ bh,
    const float* __restrict__ be,
    u16* __restrict__ h_out, u16* __restrict__ dh_out, u16* __restrict__ Se_out)
{
    const int t = threadIdx.x;
    const int lane = t & 63;
    const int w = t >> 6;
    const int wm = w & 1;
    const int wn = w >> 1;
    if (!FULL && wn == 1) return;
    const int rb = blockIdx.x * 64 + wm * 32;
    const int cb = wn * 128;
    const int l15 = lane & 15;
    const int kg  = lane >> 4;

    int r0 = rb + l15;      if (r0 > NN - 1) r0 = NN - 1;
    int r1 = rb + 16 + l15; if (r1 > NN - 1) r1 = NN - 1;
    const size_t a0off = (size_t)r0 * 128 + kg * 8;
    const size_t a1off = (size_t)r1 * 128 + kg * 8;

    f32x4 acc[2][8];
    #pragma unroll
    for (int m = 0; m < 2; ++m)
        #pragma unroll
        for (int n = 0; n < 8; ++n) acc[m][n] = (f32x4){0.f, 0.f, 0.f, 0.f};

    #pragma unroll
    for (int s = 0; s < 4; ++s) {
        const u16* __restrict__ Sp = (s == 0) ? h : (s == 1) ? dh : (s == 2) ? Sh : Se;
        #pragma unroll
        for (int k4 = 0; k4 < 4; ++k4) {
            const int ks = s * 4 + k4;     // 0..15
            const short8v a0 = *(const short8v*)(Sp + a0off + k4 * 32);
            const short8v a1 = *(const short8v*)(Sp + a1off + k4 * 32);
            const u16* bb = Bp + (((size_t)ks * 256) + cb + l15) * 32 + kg * 8;
            #pragma unroll
            for (int nf = 0; nf < 8; ++nf) {
                const short8v b = *(const short8v*)(bb + (size_t)nf * 16 * 32);
                acc[0][nf] = __builtin_amdgcn_mfma_f32_16x16x32_bf16(a0, b, acc[0][nf], 0, 0, 0);
                acc[1][nf] = __builtin_amdgcn_mfma_f32_16x16x32_bf16(a1, b, acc[1][nf], 0, 0, 0);
            }
        }
    }

    #pragma unroll
    for (int m = 0; m < 2; ++m) {
        #pragma unroll
        for (int r = 0; r < 4; ++r) {
            const int row = rb + m * 16 + kg * 4 + r;
            if (row < NN) {
                const float dg = (float)deg[row];
                if (cb == 0) {
                    #pragma unroll
                    for (int nf = 0; nf < 8; ++nf) {
                        const int col = nf * 16 + l15;
                        const float v = acc[m][nf][r] + bh[col] + dg * cvec[col];
                        h_out[(size_t)row * 128 + col] = f2bf(v);
                        if (FULL)
                            dh_out[(size_t)row * 128 + col] = f2bf(bf2f(f2bf(v)) * dg);
                    }
                } else {
                    #pragma unroll
                    for (int nf = 0; nf < 8; ++nf) {
                        const int col = nf * 16 + l15;
                        const float v = acc[m][nf][r] + dg * be[col];
                        Se_out[(size_t)row * 128 + col] = f2bf(v);
                    }
                }
            }
        }
    }
}

// ---------------- k_pool ----------------
__global__ __launch_bounds__(256) void k_pool(
    const u16* __restrict__ h, const int* __restrict__ batch,
    float* __restrict__ out)
{
    const int t = threadIdx.x;
    const int col = t & 127;
    const int half = t >> 7;
    const int base = blockIdx.x * 64 + half * 32;
    float acc = 0.f;
    int curg = -1;
    for (int i = 0; i < 32; ++i) {
        const int n = base + i;
        if (n >= NN) break;
        const int g = batch[n];
        if (g != curg) {
            if (curg >= 0) atomicAdd(&out[curg * 128 + col], acc);
            curg = g; acc = 0.f;
        }
        acc += bf2f(h[(size_t)n * 128 + col]);
    }
    if (curg >= 0) atomicAdd(&out[curg * 128 + col], acc);
}

extern "C" void kernel_launch(void* const* d_in, const int* in_sizes, int n_in,
                              void* d_out, int out_size, void* d_ws, size_t ws_size,
                              hipStream_t stream)
{
    const float* x       = (const float*)d_in[0];
    const float* p       = (const float*)d_in[1];
    const float* ea      = (const float*)d_in[2];
    const int*   eidx    = (const int*)d_in[3];
    const int*   batch   = (const int*)d_in[4];
    const float* W_embed = (const float*)d_in[5];
    const float* b_embed = (const float*)d_in[6];
    const float* W_ee    = (const float*)d_in[7];
    const float* b_ee    = (const float*)d_in[8];
    const float* Wm      = (const float*)d_in[9];
    const float* bm      = (const float*)d_in[10];
    const float* Wh      = (const float*)d_in[11];
    const float* bh      = (const float*)d_in[12];
    const float* We      = (const float*)d_in[13];
    const float* be      = (const float*)d_in[14];
    const int* send = eidx;
    const int* rec  = eidx + NE;

    // ---- workspace layout (all chunks multiples of 16B) ----
    char* w = (char*)d_ws;
    const size_t NHb = (size_t)NN * 128 * sizeof(u16);     // 12.8 MB
    u16* hA  = (u16*)w; w += NHb;
    u16* hB  = (u16*)w; w += NHb;
    u16* dhA = (u16*)w; w += NHb;
    u16* dhB = (u16*)w; w += NHb;
    u16* SeA = (u16*)w; w += NHb;
    u16* SeB = (u16*)w; w += NHb;
    u16* Sh  = (u16*)w; w += NHb;
    u16* Axp = (u16*)w;  w += (size_t)NN * 96 * 2;         // 9.6 MB
    int*  deg    = (int*)w;   w += (size_t)NN * 4;
    int*  offs   = (int*)w;   w += (size_t)(NN + 4) * 4;
    int*  cursor = (int*)w;   w += (size_t)NN * 4;
    int*  csr    = (int*)w;   w += (size_t)NE * 4;
    int*  csr_e  = (int*)w;   w += (size_t)NE * 4;
    int*  part   = (int*)w;   w += 64 * 4;
    float* Wb    = (float*)w; w += (size_t)4 * 512 * 256 * 4;
    float* cvec  = (float*)w; w += 512 * 4;
    u16*  Bp     = (u16*)w;   w += (size_t)4 * 512 * 256 * 2;
    u16*  Wpe    = (u16*)w;   w += (size_t)3 * 128 * 32 * 2;
    const size_t need = (size_t)(w - (char*)d_ws);
    if (ws_size < need) {
        fprintf(stderr, "[kernel_launch] ws_size=%zu < needed=%zu — skipping\n",
                ws_size, need);
        return;
    }

    float* out = (float*)d_out;

    hipMemsetAsync(d_out, 0, (size_t)NG * 128 * sizeof(float), stream);
    hipMemsetAsync(deg, 0, (size_t)NN * sizeof(int), stream);

    k_deg<<<NE / 256, 256, 0, stream>>>(rec, deg);
    k_prep_xp<<<NN * 48 / 256, 256, 0, stream>>>(x, p, Axp);
    k_wembed<<<3 * 128 * 32 / 256, 256, 0, stream>>>(W_embed, Wpe);
    k_embed<<<(NN + 127) / 128, 256, 0, stream>>>(Axp, Wpe, b_embed, deg, hA, dhA);
    k_wprep<<<(4 * 512 * 256 + 512 + 255) / 256, 256, 0, stream>>>(Wm, Wh, We, bm, Wb, cvec);
    k_wswz<<<4 * 512 * 256 / 256, 256, 0, stream>>>(Wb, Bp);
    k_scanA<<<NB_SCAN, 256, 0, stream>>>(deg, part);
    k_scanB<<<1, 64, 0, stream>>>(part);
    k_scanC<<<NB_SCAN, 256, 0, stream>>>(deg, part, offs, cursor);
    k_fill<<<NE / 256, 256, 0, stream>>>(send, rec, cursor, csr, csr_e);
    k_sea_se0<<<NN / 4, 256, 0, stream>>>(ea, csr_e, offs, deg, W_ee, b_ee, SeA);

    u16* h_cur = hA;   u16* h_nxt = hB;
    u16* dh_cur = dhA; u16* dh_nxt = dhB;
    u16* Se_cur = SeA; u16* Se_nxt = SeB;
    for (int l = 0; l < NL; ++l) {
        k_gather<<<NN / 4, 256, 0, stream>>>(h_cur, csr, offs, deg, Sh);
        if (l < NL - 1)
            k_dense<true><<<(NN + 63) / 64, 256, 0, stream>>>(h_cur, dh_cur, Sh, Se_cur,
                deg, Bp + (size_t)l * 512 * 256,
                cvec + l * 128, bh + l * 128, be + l * 128,
                h_nxt, dh_nxt, Se_nxt);
        else
            k_dense<false><<<(NN + 63) / 64, 256, 0, stream>>>(h_cur, dh_cur, Sh, Se_cur,
                deg, Bp + (size_t)l * 512 * 256,
                cvec + l * 128, bh + l * 128, be + l * 128,
                h_nxt, dh_nxt, Se_nxt);
        u16* tmp;
        tmp = h_cur;  h_cur  = h_nxt;  h_nxt  = tmp;
        tmp = dh_cur; dh_cur = dh_nxt; dh_nxt = tmp;
        tmp = Se_cur; Se_cur = Se_nxt; Se_nxt = tmp;
    }
    k_pool<<<(NN + 63) / 64, 256, 0, stream>>>(h_cur, batch, out);
}